// Round 1
// baseline (180.579 us; speedup 1.0000x reference)
//
#include <hip/hip_runtime.h>

// Problem constants (from reference)
#define BATCH   1024
#define EMBED   768
#define NPATCH  64      // 8x8 grid of 4x4 patches
#define PDIM    48      // 3*4*4
#define SEQ     65      // 1 cls + 64 patches

// ---------------------------------------------------------------------------
// Kernel 1: cls row.  out[b, 0, e] = pos_emb[0, e] + cls[e]
// 1024*768 floats = 196608 float4; grid 768 x 256.
// ---------------------------------------------------------------------------
__global__ __launch_bounds__(256) void cls_row_kernel(const float* __restrict__ cls,
                                                      const float* __restrict__ pos,
                                                      float* __restrict__ out) {
    int g = blockIdx.x * 256 + threadIdx.x;   // 0 .. 1024*192-1
    int b = g / 192;                          // batch
    int j = g - b * 192;                      // float4 index within the 768-wide row
    const float4* c4 = (const float4*)cls;
    const float4* p4 = (const float4*)pos;
    float4 cv = c4[j];
    float4 pv = p4[j];
    float4 o;
    o.x = cv.x + pv.x; o.y = cv.y + pv.y; o.z = cv.z + pv.z; o.w = cv.w + pv.w;
    ((float4*)out)[(size_t)b * (SEQ * EMBED / 4) + j] = o;
}

// ---------------------------------------------------------------------------
// Kernel 2: patch projection + pos add.
// One block (256 threads) per batch element b.
//   Phase 1: stage x[b] (3072 fp32, 12 KB) into LDS rearranged as patch[64][48]
//            (patch-flatten order k = c*16 + ph*4 + pw, n = gr*8 + gc).
//   Phase 2: thread t computes embeds e = r*256 + t (r = 0..2).
//            W row (48 fp32) lives in registers (float4 loads, L1/L2-hit).
//            Loop n over 64 patches: wave-uniform LDS broadcast reads of
//            patch[n][*]; 4 independent FMA chains; coalesced store with
//            fused pos_emb add.
// ---------------------------------------------------------------------------
__global__ __launch_bounds__(256) void patch_embed_kernel(const float* __restrict__ x,
                                                          const float* __restrict__ W,
                                                          const float* __restrict__ pos,
                                                          float* __restrict__ out) {
    __shared__ float patch[NPATCH][PDIM];   // 12 KB

    const int b = blockIdx.x;
    const int t = threadIdx.x;

    // ---- Phase 1: load x[b] (768 float4) and scatter into patch layout ----
    const float4* xb = (const float4*)(x + (size_t)b * 3072);
    #pragma unroll
    for (int i = 0; i < 3; ++i) {
        int idx = t + i * 256;        // float4 index 0..767 within x[b]
        float4 v = xb[idx];
        int elem = idx * 4;           // linear: c*1024 + h*32 + wcol  (wcol%4==0)
        int c   = elem >> 10;
        int rem = elem & 1023;
        int h   = rem >> 5;
        int wc  = rem & 31;
        int n = (h >> 2) * 8 + (wc >> 2);     // gr*8 + gc
        int k = c * 16 + (h & 3) * 4;         // c*16 + ph*4 (+pw via float4)
        *(float4*)&patch[n][k] = v;           // 16B aligned: k%4==0, row=192B
    }
    __syncthreads();

    float* outb = out + (size_t)b * (SEQ * EMBED) + EMBED;   // rows n=1..64

    #pragma unroll 1
    for (int r = 0; r < 3; ++r) {
        const int e = r * 256 + t;
        // W row -> registers (12 x float4). W is [768][48] row-major.
        float w[PDIM];
        const float4* wr = (const float4*)(W + e * PDIM);
        #pragma unroll
        for (int i = 0; i < 12; ++i) *(float4*)&w[i * 4] = wr[i];

        #pragma unroll 2
        for (int n = 0; n < NPATCH; ++n) {
            float a0 = 0.f, a1 = 0.f, a2 = 0.f, a3 = 0.f;
            #pragma unroll
            for (int k = 0; k < 12; ++k) {
                a0 = fmaf(patch[n][k     ], w[k     ], a0);
                a1 = fmaf(patch[n][k + 12], w[k + 12], a1);
                a2 = fmaf(patch[n][k + 24], w[k + 24], a2);
                a3 = fmaf(patch[n][k + 36], w[k + 36], a3);
            }
            float acc = (a0 + a1) + (a2 + a3);
            outb[n * EMBED + e] = acc + pos[(n + 1) * EMBED + e];
        }
    }
}

// ---------------------------------------------------------------------------
// Launch
// inputs: d_in[0]=x [1024,1,3,32,32] f32, d_in[1]=W [768,48] f32,
//         d_in[2]=cls_token [1,768] f32, d_in[3]=pos_emb [1,65,768] f32
// output: [1024,65,768] f32
// ---------------------------------------------------------------------------
extern "C" void kernel_launch(void* const* d_in, const int* in_sizes, int n_in,
                              void* d_out, int out_size, void* d_ws, size_t ws_size,
                              hipStream_t stream) {
    const float* x   = (const float*)d_in[0];
    const float* W   = (const float*)d_in[1];
    const float* cls = (const float*)d_in[2];
    const float* pos = (const float*)d_in[3];
    float* out = (float*)d_out;

    hipLaunchKernelGGL(cls_row_kernel, dim3(BATCH * (EMBED / 4) / 256), dim3(256), 0, stream,
                       cls, pos, out);
    hipLaunchKernelGGL(patch_embed_kernel, dim3(BATCH), dim3(256), 0, stream,
                       x, W, pos, out);
}

// Round 2
// 48.777 us; speedup vs baseline: 3.7021x; 3.7021x over previous
//
#include <hip/hip_runtime.h>

// ViT patch-embed: out[b,0,:] = cls + pos[0];  out[b,n+1,e] = sum_k patch[b,n,k]*W[e,k] + pos[n+1,e]
// B=1024, 64 patches of 48, E=768. Output 1024*65*768 f32 = 204.5 MB -> memory-bound floor ~34us.
// Strategy: bf16 MFMA (16x16x32), K padded 48->64 with zeros. W fragments live in
// registers across a 2-batch loop; patches staged to LDS (XOR-swizzled 16B chunks).

#define BATCH   1024
#define EMBED   768
#define NPATCH  64
#define SEQ     65
#define OUTB    (SEQ * EMBED)   // 49920

typedef __attribute__((ext_vector_type(8))) short bf16x8;   // 8 bf16 (4 VGPRs)
typedef __attribute__((ext_vector_type(4))) float f32x4;    // MFMA acc

__device__ __forceinline__ short f2bf(float f) {
    union { float f; unsigned u; } v; v.f = f;
    unsigned r = v.u + 0x7FFFu + ((v.u >> 16) & 1u);   // RNE
    return (short)(r >> 16);
}

// ---------------------------------------------------------------------------
// Kernel 1: cls row.  out[b, 0, e] = pos[0, e] + cls[e]
// ---------------------------------------------------------------------------
__global__ __launch_bounds__(256) void cls_row_kernel(const float* __restrict__ cls,
                                                      const float* __restrict__ pos,
                                                      float* __restrict__ out) {
    int g = blockIdx.x * 256 + threadIdx.x;
    int b = g / 192;
    int j = g - b * 192;
    const float4* c4 = (const float4*)cls;
    const float4* p4 = (const float4*)pos;
    float4 cv = c4[j];
    float4 pv = p4[j];
    float4 o;
    o.x = cv.x + pv.x; o.y = cv.y + pv.y; o.z = cv.z + pv.z; o.w = cv.w + pv.w;
    ((float4*)out)[(size_t)b * (OUTB / 4) + j] = o;
}

// ---------------------------------------------------------------------------
// Kernel 2: MFMA patch projection.
// Block = 256 threads (4 waves), grid = 512, 2 batches per block.
// Wave w owns e-slice [w*192, w*192+192) = 12 N-tiles of 16.
// A (patches, bf16, [64 rows][64 k] padded) in LDS, 16B-chunk XOR swizzle:
//   chunk kb of row r stored at chunk (kb ^ (r&7)).
// B (W rows as bf16) in registers: bw[12][2] fragments, loaded once per block.
// Fragment layouts (v_mfma_f32_16x16x32_bf16):
//   A: lane l holds row (l&15), k = (l>>4)*8 + j   (j=0..7 contiguous)
//   B: lane l holds col (l&15), k = (l>>4)*8 + j
//   D: lane l holds col (l&15), row = (l>>4)*4 + reg   [m89-verified]
// ---------------------------------------------------------------------------
__global__ __launch_bounds__(256, 2) void patch_embed_mfma(const float* __restrict__ x,
                                                           const float* __restrict__ W,
                                                           const float* __restrict__ pos,
                                                           float* __restrict__ out) {
    __shared__ short A[64 * 64];   // 8 KB

    const int tid  = threadIdx.x;
    const int lane = tid & 63;
    const int wave = tid >> 6;     // 0..3
    const int lr   = lane & 15;    // row (A) / col (B,D) within tile
    const int lg   = lane >> 4;    // 0..3: k-group (A,B) / row-group (D)
    const int ebase = wave * 192;

    // ---- W fragments -> registers (reused across batches) ----
    bf16x8 bw[12][2];
    #pragma unroll
    for (int nt = 0; nt < 12; ++nt) {
        const float* wrow = W + (ebase + nt * 16 + lr) * 48;
        #pragma unroll
        for (int kk = 0; kk < 2; ++kk) {
            const int k0 = kk * 32 + lg * 8;
            bf16x8 f = {0, 0, 0, 0, 0, 0, 0, 0};
            if (k0 < 48) {   // k0 in {0,8,16,24,32,40}; 48,56 stay zero (K pad)
                float4 u0 = *(const float4*)(wrow + k0);
                float4 u1 = *(const float4*)(wrow + k0 + 4);
                f[0] = f2bf(u0.x); f[1] = f2bf(u0.y); f[2] = f2bf(u0.z); f[3] = f2bf(u0.w);
                f[4] = f2bf(u1.x); f[5] = f2bf(u1.y); f[6] = f2bf(u1.z); f[7] = f2bf(u1.w);
            }
            bw[nt][kk] = f;
        }
    }

    const int b0 = blockIdx.x * 2;

    #pragma unroll 1
    for (int bi = 0; bi < 2; ++bi) {
        const int b = b0 + bi;

        __syncthreads();   // previous iteration's readers done before overwrite

        // ---- stage x[b] -> LDS bf16 patches [64][64], swizzled 16B chunks ----
        // 512 chunks of 8 bf16 (row n, k = kb*8..kb*8+7); kb 6,7 are zero pad.
        #pragma unroll
        for (int i = 0; i < 2; ++i) {
            const int cid = tid + i * 256;
            const int row = cid >> 3;            // patch n = gr*8+gc
            const int kb  = cid & 7;
            short* dst = &A[row * 64 + ((kb ^ (row & 7)) * 8)];
            bf16x8 v = {0, 0, 0, 0, 0, 0, 0, 0};
            if (kb < 6) {   // k = c*16 + ph*4 + pw; chunk = (c, ph0..ph0+1, pw 0..3)
                const int c   = kb >> 1;
                const int ph0 = (kb & 1) * 2;
                const int gr = row >> 3, gc = row & 7;
                const float* src = x + (size_t)b * 3072 + c * 1024 + (gr * 4 + ph0) * 32 + gc * 4;
                float4 u0 = *(const float4*)src;
                float4 u1 = *(const float4*)(src + 32);
                v[0] = f2bf(u0.x); v[1] = f2bf(u0.y); v[2] = f2bf(u0.z); v[3] = f2bf(u0.w);
                v[4] = f2bf(u1.x); v[5] = f2bf(u1.y); v[6] = f2bf(u1.z); v[7] = f2bf(u1.w);
            }
            *(bf16x8*)dst = v;
        }
        __syncthreads();

        // ---- compute + store, one M-tile (16 rows) at a time ----
        const size_t outbase = (size_t)b * OUTB + EMBED;   // rows n=1..64
        #pragma unroll 1
        for (int mt = 0; mt < 4; ++mt) {
            const int arow = mt * 16 + lr;
            const int sw0  = ((0 * 4 + lg) ^ (arow & 7)) * 8;
            const int sw1  = ((1 * 4 + lg) ^ (arow & 7)) * 8;
            bf16x8 a0 = *(const bf16x8*)&A[arow * 64 + sw0];   // k 0..31 slice
            bf16x8 a1 = *(const bf16x8*)&A[arow * 64 + sw1];   // k 32..63 slice

            f32x4 acc[12];
            const f32x4 zero = {0.f, 0.f, 0.f, 0.f};
            #pragma unroll
            for (int nt = 0; nt < 12; ++nt)
                acc[nt] = __builtin_amdgcn_mfma_f32_16x16x32_bf16(a0, bw[nt][0], zero, 0, 0, 0);
            #pragma unroll
            for (int nt = 0; nt < 12; ++nt)
                acc[nt] = __builtin_amdgcn_mfma_f32_16x16x32_bf16(a1, bw[nt][1], acc[nt], 0, 0, 0);

            // D: lane holds col lr, rows mt*16 + lg*4 + j
            #pragma unroll
            for (int j = 0; j < 4; ++j) {
                const int n = mt * 16 + lg * 4 + j;
                const float* prow = pos + (size_t)(n + 1) * EMBED + ebase + lr;
                float* orow = out + outbase + (size_t)n * EMBED + ebase + lr;
                #pragma unroll
                for (int nt = 0; nt < 12; ++nt)
                    orow[nt * 16] = acc[nt][j] + prow[nt * 16];
            }
        }
    }
}

// ---------------------------------------------------------------------------
extern "C" void kernel_launch(void* const* d_in, const int* in_sizes, int n_in,
                              void* d_out, int out_size, void* d_ws, size_t ws_size,
                              hipStream_t stream) {
    const float* x   = (const float*)d_in[0];
    const float* W   = (const float*)d_in[1];
    const float* cls = (const float*)d_in[2];
    const float* pos = (const float*)d_in[3];
    float* out = (float*)d_out;

    hipLaunchKernelGGL(cls_row_kernel, dim3(BATCH * (EMBED / 4) / 256), dim3(256), 0, stream,
                       cls, pos, out);
    hipLaunchKernelGGL(patch_embed_mfma, dim3(BATCH / 2), dim3(256), 0, stream,
                       x, W, pos, out);
}